// Round 14
// baseline (68.461 us; speedup 1.0000x reference)
//
#include <hip/hip_runtime.h>

// Block = 256 threads = 4 waves; each 32-lane HALF-WAVE owns one center atom.
// Block covers 8 centers; grid = nmol*2. All inter-phase state is half-wave-
// private ([cb]-indexed LDS) -> NO block barriers (validated R12).
// R14: batched LDS gathers (phase R: 16 batched reads + masked sums;
// phase B: register bucket-table + paired first-entry reads) to kill the
// serial ds_read dependency chains identified as the residual cost.
__global__ __launch_bounds__(256, 5) void aev_kernel(const int* __restrict__ species,
                                                     const float* __restrict__ coords,
                                                     float* __restrict__ out,
                                                     int nmol) {
    const int t  = threadIdx.x;
    const int w  = t >> 6;           // wave 0..3
    const int l  = t & 63;           // lane in wave
    const int h  = l >> 5;           // half 0/1
    const int lh = l & 31;           // lane in half
    const int cb = w * 2 + h;        // center slot in block 0..7
    const int b  = blockIdx.x >> 1;  // molecule
    const int g  = blockIdx.x & 1;
    const int i  = g * 8 + cb;       // center atom 0..15

    __shared__ float  scm[4][48];
    __shared__ int    ssp[4][16];
    __shared__ float4 pd[8][16];     // dx,dy,dz,d
    __shared__ float4 pf[8][16];     // rinv,fca,fcr4,0
    __shared__ float  rad[8][16][17];
    __shared__ int    vlist[8][16];
    __shared__ int    hist[8][10], sBase[8][10], sCur[8][10];
    __shared__ float4 ebuf[8][105];

    // ---- per-wave setup ----
    if (l < 48) scm[w][l] = coords[b * 48 + l];
    if (l < 16) {
        int sp = species[b * 16 + l];
        ssp[w][l] = sp;
        if (g == 0 && w == 0) out[b * 16 + l] = (float)sp;   // species (as float)
    }
    if (lh < 10) hist[cb][lh] = 0;

    const int z = lh & 7, a = lh >> 3;   // lane lh owns angular feature f = lh
    const float ang = (2.0f * (float)z + 1.0f) * 0.19634954084936207f;  // (2z+1)*pi/16
    const float czh = 0.5f * __cosf(ang);
    const float szh = 0.5f * __sinf(ang);
    const float ga  = __expf(-3.38f * (float)(a * a - a));

    const int spi = ssp[w][i];
    const float xi = scm[w][3 * i], yi = scm[w][3 * i + 1], zi = scm[w][3 * i + 2];

    // ---- pair phase (lanes lh<16 of each half) ----
    int  spl = 0;
    bool pvalid = false;
    if (lh < 16) {
        spl = ssp[w][lh];
        float dx = xi - scm[w][3 * lh], dy = yi - scm[w][3 * lh + 1], dz = zi - scm[w][3 * lh + 2];
        bool pv = (lh != i) && (spi >= 0) && (spl >= 0);
        float d2 = dx * dx + dy * dy + dz * dz;
        float d2s = pv ? d2 : 1.0f;
        float rinv = __frsqrt_rn(d2s);
        float d = d2s * rinv;
        float fca  = (pv && d <= 3.5f) ? fmaf(0.5f, __cosf(d * 0.8975979010256552f), 0.5f) : 0.0f;
        float fcr4 = (pv && d <= 5.2f) ? 0.25f * fmaf(0.5f, __cosf(d * 0.6041515809446141f), 0.5f) : 0.0f;
        pd[cb][lh] = make_float4(dx, dy, dz, d);
        pf[cb][lh] = make_float4(rinv, fca, fcr4, 0.0f);
        pvalid = fca > 0.0f;
    }
    const unsigned long long vm = __ballot(pvalid);
    const unsigned vmh = (unsigned)((vm >> (32 * h)) & 0xFFFFull);
    const int V = __popc(vmh);
    if (pvalid) {
        int idx = __popc(vmh & ((1u << lh) - 1u));
        vlist[cb][idx] = lh | (spl << 4);
    }
    const unsigned long long b0m = __ballot(lh < 16 && spl == 0);
    const unsigned long long b1m = __ballot(lh < 16 && spl == 1);
    const unsigned long long b2m = __ballot(lh < 16 && spl == 2);
    const unsigned long long b3m = __ballot(lh < 16 && spl == 3);
    const unsigned sm0 = (unsigned)((b0m >> (32 * h)) & 0xFFFFull);
    const unsigned sm1 = (unsigned)((b1m >> (32 * h)) & 0xFFFFull);
    const unsigned sm2 = (unsigned)((b2m >> (32 * h)) & 0xFFFFull);
    const unsigned sm3 = (unsigned)((b3m >> (32 * h)) & 0xFFFFull);

    // ---- radial staging: lane = (jj, rg), 8 shifts each ----
    {
        const int jj = lh & 15, rg = lh >> 4;
        float d = pd[cb][jj].w;
        float fcr4 = pf[cb][jj].z;
        #pragma unroll
        for (int rr = 0; rr < 8; ++rr) {
            int r = rg * 8 + rr;
            float e = d - (0.9f + 0.26875f * (float)r);
            rad[cb][jj][r] = fcr4 * __expf(-16.0f * e * e);
        }
    }

    // ---- triple phase: nt = V(V-1)/2 slots over 32 lanes, 4 static slots ----
    const int nt = (V * (V - 1)) >> 1;
    const int tw = 2 * V - 1;
    float caS[4], saS[4], t0S[4], r1S[4];
    int pS[4];
    #pragma unroll
    for (int slot = 0; slot < 4; ++slot) {
        pS[slot] = -1;
        const int s = slot * 32 + lh;
        if (s < nt) {
            float disc = (float)(tw * tw - 8 * s);
            int aa = (int)floorf(0.5f * ((float)tw - sqrtf(disc)));
            aa = aa < 0 ? 0 : (aa > V - 2 ? V - 2 : aa);
            int offa = (aa * (2 * V - 1 - aa)) >> 1;
            if (s < offa) { --aa; offa = (aa * (2 * V - 1 - aa)) >> 1; }
            else { int offn = ((aa + 1) * (2 * V - 2 - aa)) >> 1; if (s >= offn) { ++aa; offa = offn; } }
            const int bb = aa + 1 + (s - offa);
            const int va = vlist[cb][aa], vb = vlist[cb][bb];
            const int j = va & 15, spj = va >> 4;
            const int k = vb & 15, spk = vb >> 4;
            float4 Pj = pd[cb][j], Pk = pd[cb][k];
            float4 Fj = pf[cb][j], Fk = pf[cb][k];
            float dot = Pj.x * Pk.x + Pj.y * Pk.y + Pj.z * Pk.z;
            float ca = 0.95f * dot * Fj.x * Fk.x;
            ca = fminf(0.95f, fmaxf(-0.95f, ca));
            float s2 = 1.0f - ca * ca;                 // >= 0.0975
            float sa = s2 * __frsqrt_rn(s2);
            float davg = 0.5f * (Pj.w + Pk.w);
            float e0 = davg - 0.9f;
            float t0 = 2.0f * Fj.y * Fk.y * __expf(-8.0f * e0 * e0);
            float r1 = __expf(10.4f * davg - 12.74f);
            int lo = spj < spk ? spj : spk, hi = spj < spk ? spk : spj;
            int p = lo * 4 + hi - ((lo * (lo + 1)) >> 1);
            atomicAdd(&hist[cb][p], 1);
            caS[slot] = ca; saS[slot] = sa; t0S[slot] = t0; r1S[slot] = r1; pS[slot] = p;
        }
    }

    // ---- exclusive prefix over 10 buckets (half-private) ----
    if (lh < 10) {
        int sum = 0;
        for (int qq = 0; qq < lh; ++qq) sum += hist[cb][qq];
        sBase[cb][lh] = sum;
        sCur[cb][lh] = sum;
    }

    // ---- bucket fill ----
    #pragma unroll
    for (int slot = 0; slot < 4; ++slot) {
        if (pS[slot] >= 0) {
            int idx = atomicAdd(&sCur[cb][pS[slot]], 1);
            ebuf[cb][idx] = make_float4(caS[slot], saS[slot], t0S[slot], r1S[slot]);
        }
    }

    float* base_o = out + (size_t)nmol * 16 + (size_t)(b * 16 + i) * 384;
    const bool a1 = (a & 1), a2 = (a & 2) != 0;

    // per-feature angular contribution of one triple record
    auto CONTRIB = [&](float4 v) -> float {
        float c1 = fmaf(czh, v.x, fmaf(szh, v.y, 0.5f));  // (1+cos(th-shfz))/2
        float c2 = c1 * c1;
        float c4 = c2 * c2;
        float c8 = c4 * c4;
        float c16 = c8 * c8;
        float c32 = c16 * c16;
        float tt = v.z;
        float rsq = v.w * v.w;
        tt = a1 ? tt * v.w : tt;
        tt = a2 ? tt * rsq : tt;                           // tt = t0 * r1^a
        return tt * c32;
    };

    // ---- phase B: bucket table in registers, paired first-entry reads ----
    {
        int bb_[10];
        #pragma unroll
        for (int p = 0; p < 10; ++p) bb_[p] = sBase[cb][p];   // batched LDS reads

        #pragma unroll
        for (int pp = 0; pp < 5; ++pp) {
            const int P0 = 2 * pp, P1 = 2 * pp + 1;
            const int B0 = bb_[P0], B1 = bb_[P1];
            const int E0 = (P0 < 9) ? bb_[P1] : nt;           // end of bucket P0
            const int E1 = (P1 < 9) ? bb_[P1 + 1] : nt;       // end of bucket P1
            const int N0 = E0 - B0, N1 = E1 - B1;
            // issue both first-entry reads together (addresses clamped; result
            // select-guarded so uninitialized LDS (even NaN) cannot leak)
            float4 v0 = ebuf[cb][B0 < 104 ? B0 : 104];
            float4 v1 = ebuf[cb][B1 < 104 ? B1 : 104];
            float acc0 = (N0 > 0) ? CONTRIB(v0) : 0.0f;
            float acc1 = (N1 > 0) ? CONTRIB(v1) : 0.0f;
            for (int e = B0 + 1; e < E0; ++e) acc0 += CONTRIB(ebuf[cb][e]);
            for (int e = B1 + 1; e < E1; ++e) acc1 += CONTRIB(ebuf[cb][e]);
            base_o[64 + P0 * 32 + lh] = acc0 * ga;
            base_o[64 + P1 * 32 + lh] = acc1 * ga;
        }
    }

    // ---- phase R: 16 batched reads + two masked sums ----
    {
        const int r_ = lh & 15;
        const int hb = lh >> 4;          // 0/1
        float rvj[16];
        #pragma unroll
        for (int jj = 0; jj < 16; ++jj) rvj[jj] = rad[cb][jj][r_];  // independent reads
        const unsigned mA = hb ? sm1 : sm0;
        const unsigned mB = hb ? sm3 : sm2;
        float rvA = 0.0f, rvB = 0.0f;
        #pragma unroll
        for (int jj = 0; jj < 16; ++jj) {
            rvA += ((mA >> jj) & 1u) ? rvj[jj] : 0.0f;
            rvB += ((mB >> jj) & 1u) ? rvj[jj] : 0.0f;
        }
        base_o[hb * 16 + r_] = rvA;          // species hb
        base_o[(hb + 2) * 16 + r_] = rvB;    // species hb+2
    }
}

extern "C" void kernel_launch(void* const* d_in, const int* in_sizes, int n_in,
                              void* d_out, int out_size, void* d_ws, size_t ws_size,
                              hipStream_t stream) {
    const int*   species = (const int*)d_in[0];
    const float* coords  = (const float*)d_in[1];
    float*       out     = (float*)d_out;
    int nmol = in_sizes[0] / 16;   // 512
    aev_kernel<<<nmol * 2, 256, 0, stream>>>(species, coords, out, nmol);
}